// Round 1
// baseline (3946.773 us; speedup 1.0000x reference)
//
#include <hip/hip_runtime.h>

typedef unsigned int u32;

#define FIN 384
#define HD  128
#define PD  128
#define RD  16

// ---------------------------------------------------------------------------
// Graph preprocessing: histograms -> exclusive scan -> CSR fill
// ---------------------------------------------------------------------------
__global__ void hist_k(const int* __restrict__ src, const int* __restrict__ dst,
                       u32* __restrict__ cs, u32* __restrict__ cd, int E) {
  int i = blockIdx.x * 256 + threadIdx.x;
  if (i < E) {
    atomicAdd(&cs[src[i]], 1u);
    atomicAdd(&cd[dst[i]], 1u);
  }
}

__global__ __launch_bounds__(1024)
void scan_k(const u32* __restrict__ cnt, u32* __restrict__ off,
            u32* __restrict__ cur, int n) {
  __shared__ u32 sh[1024];
  __shared__ u32 carry;
  if (threadIdx.x == 0) carry = 0u;
  __syncthreads();
  for (int base = 0; base < n; base += 1024) {
    int i = base + (int)threadIdx.x;
    u32 v = (i < n) ? cnt[i] : 0u;
    sh[threadIdx.x] = v;
    __syncthreads();
    for (int s = 1; s < 1024; s <<= 1) {
      u32 t = (threadIdx.x >= (u32)s) ? sh[threadIdx.x - s] : 0u;
      __syncthreads();
      sh[threadIdx.x] += t;
      __syncthreads();
    }
    u32 excl = carry + sh[threadIdx.x] - v;   // exclusive prefix
    if (i < n) { off[i] = excl; cur[i] = excl; }
    __syncthreads();
    if (threadIdx.x == 1023) carry += sh[1023];
    __syncthreads();
  }
}

__global__ void fill_k(const int* __restrict__ src, const int* __restrict__ dst,
                       u32* __restrict__ cur_s, u32* __restrict__ cur_d,
                       u32* __restrict__ csrD_src, u32* __restrict__ csrS_src,
                       u32* __restrict__ csrS_dst, int E) {
  int i = blockIdx.x * 256 + threadIdx.x;
  if (i >= E) return;
  int s = src[i], d = dst[i];
  u32 pd = atomicAdd(&cur_d[d], 1u);
  csrD_src[pd] = (u32)s;
  u32 ps = atomicAdd(&cur_s[s], 1u);
  csrS_src[ps] = (u32)s;
  csrS_dst[ps] = (u32)d;
}

__global__ void dinv_k(const u32* __restrict__ cd, float* __restrict__ dinv, int n) {
  int i = blockIdx.x * 256 + threadIdx.x;
  if (i < n) dinv[i] = 1.0f / sqrtf((float)(cd[i] + 1u));  // +1 self-loop
}

// ---------------------------------------------------------------------------
// GCN aggregation (dst-CSR gather): out[n] = dinv[n]^2*xw[n] + sum_nbr dinv[n]*dinv[s]*xw[s] + b
// one wave per node, 128 feats = 64 lanes x float2
// ---------------------------------------------------------------------------
__global__ void gcn_agg_k(const float* __restrict__ xw, const float* __restrict__ dinv,
                          const u32* __restrict__ off, const u32* __restrict__ cnt,
                          const u32* __restrict__ nbr, const float* __restrict__ bias,
                          float* __restrict__ outp, int n) {
  int node = (blockIdx.x * blockDim.x + threadIdx.x) >> 6;
  int lane = threadIdx.x & 63;
  if (node >= n) return;
  float di = dinv[node];
  float2 v = ((const float2*)(xw + (size_t)node * HD))[lane];
  float2 acc = make_float2(di * di * v.x, di * di * v.y);
  u32 o = off[node], c = cnt[node];
  for (u32 i = o; i < o + c; ++i) {
    int s = (int)nbr[i];
    float w = di * dinv[s];
    float2 u = ((const float2*)(xw + (size_t)s * HD))[lane];
    acc.x = fmaf(w, u.x, acc.x);
    acc.y = fmaf(w, u.y, acc.y);
  }
  float2 b = ((const float2*)bias)[lane];
  ((float2*)(outp + (size_t)node * HD))[lane] = make_float2(acc.x + b.x, acc.y + b.y);
}

// ---------------------------------------------------------------------------
// Edge scores: scores[i] = dot(t_info[src], g_info[dst]) / sqrt(384), CSR-src order.
// 16 lanes per entry, float4 loads.
// ---------------------------------------------------------------------------
__global__ void scores_k(const u32* __restrict__ csrS_src, const u32* __restrict__ csrS_dst,
                         const float* __restrict__ tinfo, const float* __restrict__ ginfo,
                         float* __restrict__ scores, int E) {
  int g = blockIdx.x * 256 + threadIdx.x;
  int entry = g >> 4;
  int l = g & 15;
  if (entry >= E) return;
  int s = (int)csrS_src[entry], d = (int)csrS_dst[entry];
  const float4* tp = (const float4*)(tinfo + (size_t)s * FIN);
  const float4* gp = (const float4*)(ginfo + (size_t)d * FIN);
  float dot = 0.f;
#pragma unroll
  for (int k = 0; k < 6; ++k) {
    float4 a = tp[l + 16 * k];
    float4 b = gp[l + 16 * k];
    dot += a.x * b.x + a.y * b.y + a.z * b.z + a.w * b.w;
  }
#pragma unroll
  for (int m = 8; m >= 1; m >>= 1) dot += __shfl_xor(dot, m);
  if (l == 0) scores[entry] = dot * 0.05103103630798288f;  // 1/sqrt(384)
}

// ---------------------------------------------------------------------------
// Fused scatter-softmax + weighted aggregate + residual. One wave per src node.
// x_fused[n] = sum_e softmax(scores)_e * v[dst_e] + x[n]
// ---------------------------------------------------------------------------
__global__ void attn_k(const u32* __restrict__ off, const u32* __restrict__ cnt,
                       const u32* __restrict__ csrS_dst, const float* __restrict__ scores,
                       const float* __restrict__ vmat, const float* __restrict__ x,
                       float* __restrict__ xf, int n) {
  int node = (blockIdx.x * blockDim.x + threadIdx.x) >> 6;
  int lane = threadIdx.x & 63;
  if (node >= n) return;
  u32 o = off[node], c = cnt[node];
  float acc[6] = {0.f, 0.f, 0.f, 0.f, 0.f, 0.f};
  if (c > 0) {
    float m = -1e30f;
    for (u32 i = o + lane; i < o + c; i += 64) m = fmaxf(m, scores[i]);
#pragma unroll
    for (int s = 32; s >= 1; s >>= 1) m = fmaxf(m, __shfl_xor(m, s));
    float den = 0.f;
    for (u32 i = o + lane; i < o + c; i += 64) den += expf(scores[i] - m);
#pragma unroll
    for (int s = 32; s >= 1; s >>= 1) den += __shfl_xor(den, s);
    float invden = 1.0f / den;
    for (u32 i = o; i < o + c; ++i) {
      int d = (int)csrS_dst[i];
      float w = expf(scores[i] - m) * invden;
      const float* vp = vmat + (size_t)d * FIN;
#pragma unroll
      for (int k = 0; k < 6; ++k) acc[k] = fmaf(w, vp[lane + 64 * k], acc[k]);
    }
  }
  const float* xp = x + (size_t)node * FIN;
  float* op = xf + (size_t)node * FIN;
#pragma unroll
  for (int k = 0; k < 6; ++k) op[lane + 64 * k] = acc[k] + xp[lane + 64 * k];
}

// ---------------------------------------------------------------------------
// Tiled fp32 GEMM, 64x64 tile, 256 threads, 4x4 micro-tile, K-step 16.
// EPI: 0 = none, 1 = +bias, 2 = relu(+bias),
//      3 = right-fused: temp[r, rr] += sum_cols (acc+bias)*x[r, f]   (atomic)
//      4 = left-fused:  p_t[r, p]  = sum_r16 (acc+bias)*temp[r, rmod] (direct)
// ---------------------------------------------------------------------------
template <int EPI>
__global__ __launch_bounds__(256)
void gemm_k(const float* __restrict__ Ap, const float* __restrict__ Wp,
            const float* __restrict__ bias, float* __restrict__ Cp,
            const float* __restrict__ xv, float* __restrict__ tmp,
            int M, int K, int Nc) {
  __shared__ float As[16][65];
  __shared__ float Ws[16][64];
  const int tx = threadIdx.x & 15;
  const int ty = threadIdx.x >> 4;
  const int row0 = blockIdx.y << 6;
  const int col0 = blockIdx.x << 6;
  const int kr = threadIdx.x >> 6;
  const int cc = threadIdx.x & 63;
  float acc[4][4] = {};

  for (int k0 = 0; k0 < K; k0 += 16) {
#pragma unroll
    for (int i = 0; i < 4; ++i) {
      int r = row0 + ty * 4 + i;
      As[tx][ty * 4 + i] = (r < M) ? Ap[(size_t)r * K + (k0 + tx)] : 0.f;
    }
#pragma unroll
    for (int i = 0; i < 4; ++i)
      Ws[kr + 4 * i][cc] = Wp[(size_t)(k0 + kr + 4 * i) * Nc + (col0 + cc)];
    __syncthreads();
#pragma unroll
    for (int kk = 0; kk < 16; ++kk) {
      float a[4], b[4];
#pragma unroll
      for (int i = 0; i < 4; ++i) a[i] = As[kk][ty * 4 + i];
#pragma unroll
      for (int j = 0; j < 4; ++j) b[j] = Ws[kk][tx * 4 + j];
#pragma unroll
      for (int i = 0; i < 4; ++i)
#pragma unroll
        for (int j = 0; j < 4; ++j) acc[i][j] = fmaf(a[i], b[j], acc[i][j]);
    }
    __syncthreads();
  }

  if constexpr (EPI <= 2) {
#pragma unroll
    for (int i = 0; i < 4; ++i) {
      int r = row0 + ty * 4 + i;
      if (r >= M) continue;
#pragma unroll
      for (int j = 0; j < 4; ++j) {
        int col = col0 + tx * 4 + j;
        float v = acc[i][j];
        if constexpr (EPI >= 1) v += bias[col];
        if constexpr (EPI == 2) v = fmaxf(v, 0.f);
        Cp[(size_t)r * Nc + col] = v;
      }
    }
  } else if constexpr (EPI == 3) {
    // cols are r*384+f; a 64-col tile sits inside one r (384 % 64 == 0)
    const int rr = col0 / FIN;
    const int fbase = col0 % FIN;
#pragma unroll
    for (int i = 0; i < 4; ++i) {
      int r = row0 + ty * 4 + i;
      float partial = 0.f;
      if (r < M) {
#pragma unroll
        for (int j = 0; j < 4; ++j) {
          int col = col0 + tx * 4 + j;
          partial += (acc[i][j] + bias[col]) * xv[(size_t)r * FIN + (fbase + tx * 4 + j)];
        }
      }
      partial += __shfl_xor(partial, 1);
      partial += __shfl_xor(partial, 2);
      partial += __shfl_xor(partial, 4);
      partial += __shfl_xor(partial, 8);
      if (tx == 0 && r < M) atomicAdd(&tmp[(size_t)r * RD + rr], partial);
    }
  } else {  // EPI == 4: cols are p*16 + r16; each thread's 4 cols share one p
#pragma unroll
    for (int i = 0; i < 4; ++i) {
      int r = row0 + ty * 4 + i;
      float partial = 0.f;
      if (r < M) {
#pragma unroll
        for (int j = 0; j < 4; ++j) {
          int col = col0 + tx * 4 + j;
          partial += (acc[i][j] + bias[col]) * tmp[(size_t)r * RD + (col & 15)];
        }
      }
      partial += __shfl_xor(partial, 1);
      partial += __shfl_xor(partial, 2);
      if ((tx & 3) == 0 && r < M) {
        int p = (col0 + tx * 4) >> 4;
        Cp[(size_t)r * PD + p] = partial;
      }
    }
  }
}

// ---------------------------------------------------------------------------
// Final: in-place row-normalize p_t, p_g; alignment = dot of normalized rows.
// ---------------------------------------------------------------------------
__global__ void final_k(float* __restrict__ out, int n) {
  int node = (blockIdx.x * blockDim.x + threadIdx.x) >> 6;
  int lane = threadIdx.x & 63;
  if (node >= n) return;
  float* pt = out + n + (size_t)node * PD;
  float* pg = out + n + (size_t)n * PD + (size_t)node * PD;
  float2 t = ((float2*)pt)[lane];
  float2 g = ((float2*)pg)[lane];
  float tt = t.x * t.x + t.y * t.y;
  float gg = g.x * g.x + g.y * g.y;
  float tg = t.x * g.x + t.y * g.y;
#pragma unroll
  for (int s = 32; s >= 1; s >>= 1) {
    tt += __shfl_xor(tt, s);
    gg += __shfl_xor(gg, s);
    tg += __shfl_xor(tg, s);
  }
  float invt = 1.0f / fmaxf(sqrtf(tt), 1e-12f);
  float invg = 1.0f / fmaxf(sqrtf(gg), 1e-12f);
  ((float2*)pt)[lane] = make_float2(t.x * invt, t.y * invt);
  ((float2*)pg)[lane] = make_float2(g.x * invg, g.y * invg);
  if (lane == 0) out[node] = tg * invt * invg;
}

// ---------------------------------------------------------------------------
static void rgemm(int epi, const float* A, const float* W, const float* b, float* C,
                  const float* xv, float* tmp, int M, int K, int Nc, hipStream_t s) {
  dim3 grid(Nc / 64, (M + 63) / 64);
  switch (epi) {
    case 0: gemm_k<0><<<grid, 256, 0, s>>>(A, W, b, C, xv, tmp, M, K, Nc); break;
    case 1: gemm_k<1><<<grid, 256, 0, s>>>(A, W, b, C, xv, tmp, M, K, Nc); break;
    case 2: gemm_k<2><<<grid, 256, 0, s>>>(A, W, b, C, xv, tmp, M, K, Nc); break;
    case 3: gemm_k<3><<<grid, 256, 0, s>>>(A, W, b, C, xv, tmp, M, K, Nc); break;
    case 4: gemm_k<4><<<grid, 256, 0, s>>>(A, W, b, C, xv, tmp, M, K, Nc); break;
  }
}

extern "C" void kernel_launch(void* const* d_in, const int* in_sizes, int n_in,
                              void* d_out, int out_size, void* d_ws, size_t ws_size,
                              hipStream_t stream) {
  const float* x      = (const float*)d_in[0];
  const int*   ei     = (const int*)d_in[1];
  const float* W_gcn1 = (const float*)d_in[2];
  const float* b_gcn1 = (const float*)d_in[3];
  const float* W_ti   = (const float*)d_in[4];
  const float* b_ti   = (const float*)d_in[5];
  const float* W_gi   = (const float*)d_in[6];
  const float* b_gi   = (const float*)d_in[7];
  const float* W_v    = (const float*)d_in[8];
  const float* b_v    = (const float*)d_in[9];
  const float* Wl1    = (const float*)d_in[10];
  const float* bl1    = (const float*)d_in[11];
  const float* Wl2    = (const float*)d_in[12];
  const float* bl2    = (const float*)d_in[13];
  const float* Wr1    = (const float*)d_in[14];
  const float* br1    = (const float*)d_in[15];
  const float* Wr2    = (const float*)d_in[16];
  const float* br2    = (const float*)d_in[17];
  const float* W_gcn2 = (const float*)d_in[18];
  const float* b_gcn2 = (const float*)d_in[19];
  const float* W_gp   = (const float*)d_in[20];
  const float* b_gp   = (const float*)d_in[21];

  const int n = in_sizes[0] / FIN;   // 50000
  const int E = in_sizes[1] / 2;     // 500000
  const int* src = ei;
  const int* dst = ei + E;

  // -------- workspace carve (≈295 MB) --------
  char* wsp = (char*)d_ws;
  auto carve = [&](size_t bytes) -> void* {
    void* p = (void*)wsp;
    wsp += (bytes + 255) & ~(size_t)255;
    return p;
  };
  u32* cnt_s    = (u32*)carve((size_t)n * 4);
  u32* cnt_d    = (u32*)carve((size_t)n * 4);
  u32* off_s    = (u32*)carve((size_t)n * 4);
  u32* off_d    = (u32*)carve((size_t)n * 4);
  u32* cur_s    = (u32*)carve((size_t)n * 4);
  u32* cur_d    = (u32*)carve((size_t)n * 4);
  u32* csrD_src = (u32*)carve((size_t)E * 4);
  u32* csrS_src = (u32*)carve((size_t)E * 4);
  u32* csrS_dst = (u32*)carve((size_t)E * 4);
  float* dinv   = (float*)carve((size_t)n * 4);
  float* scores = (float*)carve((size_t)E * 4);
  float* temp   = (float*)carve((size_t)n * RD * 4);
  float* bufH1  = (float*)carve((size_t)n * HD * 4);   // xw1, then xw2
  float* g_emb  = (float*)carve((size_t)n * HD * 4);
  float* A      = (float*)carve((size_t)n * FIN * 4);  // t_info -> x_fused
  float* B      = (float*)carve((size_t)n * FIN * 4);  // g_info -> relu_l | relu_r
  float* C      = (float*)carve((size_t)n * FIN * 4);  // v

  float* out    = (float*)d_out;
  float* pt_raw = out + n;                       // p_t slot, raw then normalized in place
  float* pg_raw = out + n + (size_t)n * PD;      // p_g slot
  float* g2     = out + n + (size_t)2 * n * PD;  // g2 slot (also an output)

  float* relu_l = B;
  float* relu_r = B + (size_t)n * 192;

  // 1) CSR build + degrees
  hipMemsetAsync(cnt_s, 0, (size_t)n * 4, stream);
  hipMemsetAsync(cnt_d, 0, (size_t)n * 4, stream);
  hist_k<<<(E + 255) / 256, 256, 0, stream>>>(src, dst, cnt_s, cnt_d, E);
  scan_k<<<1, 1024, 0, stream>>>(cnt_s, off_s, cur_s, n);
  scan_k<<<1, 1024, 0, stream>>>(cnt_d, off_d, cur_d, n);
  fill_k<<<(E + 255) / 256, 256, 0, stream>>>(src, dst, cur_s, cur_d,
                                              csrD_src, csrS_src, csrS_dst, E);
  dinv_k<<<(n + 255) / 256, 256, 0, stream>>>(cnt_d, dinv, n);

  // 2) GCN1: xw1 = x @ W_gcn1; aggregate + bias -> g_emb
  rgemm(0, x, W_gcn1, nullptr, bufH1, nullptr, nullptr, n, FIN, HD, stream);
  gcn_agg_k<<<(n + 3) / 4, 256, 0, stream>>>(bufH1, dinv, off_d, cnt_d, csrD_src,
                                             b_gcn1, g_emb, n);

  // 3) Cross fusion
  rgemm(1, x, W_ti, b_ti, A, nullptr, nullptr, n, FIN, FIN, stream);        // t_info
  rgemm(1, g_emb, W_gi, b_gi, B, nullptr, nullptr, n, HD, FIN, stream);     // g_info
  rgemm(1, x, W_v, b_v, C, nullptr, nullptr, n, FIN, FIN, stream);          // v
  scores_k<<<(E + 15) / 16, 256, 0, stream>>>(csrS_src, csrS_dst, A, B, scores, E);
  attn_k<<<(n + 3) / 4, 256, 0, stream>>>(off_s, cnt_s, csrS_dst, scores, C, x, A, n);

  // 4) Generators (A = x_fused; B reused for relu_l / relu_r)
  rgemm(2, A, Wl1, bl1, relu_l, nullptr, nullptr, n, FIN, 192, stream);
  rgemm(2, A, Wr1, br1, relu_r, nullptr, nullptr, n, FIN, 192, stream);

  hipMemsetAsync(temp, 0, (size_t)n * RD * 4, stream);
  // right path fused: temp[n,r] = sum_f (relu_r@Wr2 + br2)[n, r*384+f] * x[n,f]
  rgemm(3, relu_r, Wr2, br2, nullptr, x, temp, n, 192, RD * FIN, stream);
  // left path fused: p_t[n,p] = sum_r (relu_l@Wl2 + bl2)[n, p*16+r] * temp[n,r]
  rgemm(4, relu_l, Wl2, bl2, pt_raw, nullptr, temp, n, 192, PD * RD, stream);

  // 5) GCN2 + graph projection
  rgemm(0, pt_raw, W_gcn2, nullptr, bufH1, nullptr, nullptr, n, PD, HD, stream);
  gcn_agg_k<<<(n + 3) / 4, 256, 0, stream>>>(bufH1, dinv, off_d, cnt_d, csrD_src,
                                             b_gcn2, g2, n);
  rgemm(1, g2, W_gp, b_gp, pg_raw, nullptr, nullptr, n, HD, PD, stream);

  // 6) normalize + alignment
  final_k<<<(n + 3) / 4, 256, 0, stream>>>(out, n);
}

// Round 2
// 1315.909 us; speedup vs baseline: 2.9993x; 2.9993x over previous
//
#include <hip/hip_runtime.h>

typedef unsigned int u32;
typedef unsigned short u16;
typedef short s16x8 __attribute__((ext_vector_type(8)));
typedef u16 u16x8 __attribute__((ext_vector_type(8)));
typedef float f32x4 __attribute__((ext_vector_type(4)));

#define FIN 384
#define HD  128
#define PD  128
#define RD  16

#define GLOAD16(g, l)                                                          \
  __builtin_amdgcn_global_load_lds(                                            \
      (const __attribute__((address_space(1))) void*)(g),                      \
      (__attribute__((address_space(3))) void*)(l), 16, 0, 0)

__device__ __forceinline__ u16 f2bf(float f) {
  u32 u = __float_as_uint(f);
  u32 r = (u + 0x7fffu + ((u >> 16) & 1u)) >> 16;   // RNE
  return (u16)r;
}
__device__ __forceinline__ float bf2f(u16 h) {
  return __uint_as_float(((u32)h) << 16);
}

// ---------------------------------------------------------------------------
// converts
// ---------------------------------------------------------------------------
__global__ void cvt_k(const float* __restrict__ in, u16* __restrict__ out, int n4) {
  int i = blockIdx.x * 256 + threadIdx.x;
  if (i >= n4) return;
  float4 f = ((const float4*)in)[i];
  ushort4 o;
  o.x = f2bf(f.x); o.y = f2bf(f.y); o.z = f2bf(f.z); o.w = f2bf(f.w);
  ((ushort4*)out)[i] = o;
}

// WT[c][k] = bf16(W[k][c]);  W is [K][N]
__global__ void cvtT_k(const float* __restrict__ W, u16* __restrict__ WT, int K, int N) {
  int i = blockIdx.x * 256 + threadIdx.x;
  if (i >= K * N) return;
  int c = i / K, k = i - c * K;
  WT[i] = f2bf(W[(size_t)k * N + c]);
}

// ---------------------------------------------------------------------------
// Graph preprocessing
// ---------------------------------------------------------------------------
__global__ void hist_k(const int* __restrict__ src, const int* __restrict__ dst,
                       u32* __restrict__ cs, u32* __restrict__ cd, int E) {
  int i = blockIdx.x * 256 + threadIdx.x;
  if (i < E) {
    atomicAdd(&cs[src[i]], 1u);
    atomicAdd(&cd[dst[i]], 1u);
  }
}

__global__ __launch_bounds__(1024)
void scanA_k(const u32* __restrict__ cnt, u32* __restrict__ off,
             u32* __restrict__ bsum, int n) {
  __shared__ u32 sh[1024];
  int i = blockIdx.x * 1024 + (int)threadIdx.x;
  u32 v = (i < n) ? cnt[i] : 0u;
  sh[threadIdx.x] = v;
  __syncthreads();
  for (int s = 1; s < 1024; s <<= 1) {
    u32 t = (threadIdx.x >= (u32)s) ? sh[threadIdx.x - s] : 0u;
    __syncthreads();
    sh[threadIdx.x] += t;
    __syncthreads();
  }
  if (i < n) off[i] = sh[threadIdx.x] - v;       // local exclusive
  if (threadIdx.x == 1023) bsum[blockIdx.x] = sh[1023];
}

__global__ void scanB_k(u32* __restrict__ bsum, int nb) {   // nb <= 64, 1 wave
  int l = threadIdx.x;
  u32 v = (l < nb) ? bsum[l] : 0u;
  for (int s = 1; s < 64; s <<= 1) {
    u32 t = __shfl_up(v, s);
    if (l >= s) v += t;
  }
  if (l < nb) bsum[l] = v;                       // inclusive
}

__global__ __launch_bounds__(1024)
void scanC_k(u32* __restrict__ off, u32* __restrict__ cur,
             const u32* __restrict__ bsum, int n) {
  int b = blockIdx.x;
  int i = b * 1024 + (int)threadIdx.x;
  if (i >= n) return;
  u32 add = (b > 0) ? bsum[b - 1] : 0u;
  u32 o = off[i] + add;
  off[i] = o;
  cur[i] = o;
}

__global__ void fill_k(const int* __restrict__ src, const int* __restrict__ dst,
                       u32* __restrict__ cur_s, u32* __restrict__ cur_d,
                       u32* __restrict__ csrD_src, u32* __restrict__ csrS_dst, int E) {
  int i = blockIdx.x * 256 + threadIdx.x;
  if (i >= E) return;
  int s = src[i], d = dst[i];
  u32 pd = atomicAdd(&cur_d[d], 1u);
  csrD_src[pd] = (u32)s;
  u32 ps = atomicAdd(&cur_s[s], 1u);
  csrS_dst[ps] = (u32)d;
}

// csrS_src regenerated from offsets: store src id per entry for scores_k
__global__ void srcid_k(const u32* __restrict__ off, const u32* __restrict__ cnt,
                        u32* __restrict__ csrS_src, int n) {
  int node = blockIdx.x * 256 + threadIdx.x;
  if (node >= n) return;
  u32 o = off[node], c = cnt[node];
  for (u32 i = o; i < o + c; ++i) csrS_src[i] = (u32)node;
}

__global__ void dinv_k(const u32* __restrict__ cd, float* __restrict__ dinv, int n) {
  int i = blockIdx.x * 256 + threadIdx.x;
  if (i < n) dinv[i] = 1.0f / sqrtf((float)(cd[i] + 1u));
}

// ---------------------------------------------------------------------------
// GCN aggregation, bf16 in, fp32/bf16 out
// ---------------------------------------------------------------------------
template <int WF32, int WBF>
__global__ void gcn_agg_k(const u16* __restrict__ xw, const float* __restrict__ dinv,
                          const u32* __restrict__ off, const u32* __restrict__ cnt,
                          const u32* __restrict__ nbr, const float* __restrict__ bias,
                          float* __restrict__ outf, u16* __restrict__ outb, int n) {
  int node = (blockIdx.x * blockDim.x + threadIdx.x) >> 6;
  int lane = threadIdx.x & 63;
  if (node >= n) return;
  float di = dinv[node];
  ushort2 v = ((const ushort2*)(xw + (size_t)node * HD))[lane];
  float ax = di * di * bf2f(v.x), ay = di * di * bf2f(v.y);
  u32 o = off[node], c = cnt[node];
  for (u32 i = o; i < o + c; ++i) {
    int s = (int)nbr[i];
    float w = di * dinv[s];
    ushort2 u = ((const ushort2*)(xw + (size_t)s * HD))[lane];
    ax = fmaf(w, bf2f(u.x), ax);
    ay = fmaf(w, bf2f(u.y), ay);
  }
  float2 b = ((const float2*)bias)[lane];
  ax += b.x; ay += b.y;
  if (WF32) ((float2*)(outf + (size_t)node * HD))[lane] = make_float2(ax, ay);
  if (WBF) {
    ushort2 ob; ob.x = f2bf(ax); ob.y = f2bf(ay);
    ((ushort2*)(outb + (size_t)node * HD))[lane] = ob;
  }
}

// ---------------------------------------------------------------------------
// Edge scores (bf16 tables)
// ---------------------------------------------------------------------------
__global__ void scores_k(const u32* __restrict__ csrS_src, const u32* __restrict__ csrS_dst,
                         const u16* __restrict__ ti, const u16* __restrict__ gi,
                         float* __restrict__ scores, int E) {
  int g = blockIdx.x * 256 + threadIdx.x;
  int e = g >> 4, l = g & 15;
  if (e >= E) return;
  const u16* tp = ti + (size_t)csrS_src[e] * FIN;
  const u16* gp = gi + (size_t)csrS_dst[e] * FIN;
  float dot = 0.f;
#pragma unroll
  for (int c = 0; c < 3; ++c) {
    u16x8 a = *(const u16x8*)(tp + c * 128 + l * 8);
    u16x8 b = *(const u16x8*)(gp + c * 128 + l * 8);
#pragma unroll
    for (int q = 0; q < 8; ++q) dot = fmaf(bf2f(a[q]), bf2f(b[q]), dot);
  }
#pragma unroll
  for (int m2 = 8; m2 >= 1; m2 >>= 1) dot += __shfl_xor(dot, m2);
  if (l == 0) scores[e] = dot * 0.05103103630798288f;  // 1/sqrt(384)
}

// ---------------------------------------------------------------------------
// Fused scatter-softmax + aggregate + residual; bf16 v, bf16 out
// ---------------------------------------------------------------------------
__global__ void attn_k(const u32* __restrict__ off, const u32* __restrict__ cnt,
                       const u32* __restrict__ csrS_dst, const float* __restrict__ scores,
                       const u16* __restrict__ vmat, const float* __restrict__ x,
                       u16* __restrict__ xf, int n) {
  int node = (blockIdx.x * blockDim.x + threadIdx.x) >> 6;
  int lane = threadIdx.x & 63;
  if (node >= n) return;
  u32 o = off[node], c = cnt[node];
  float acc[6] = {0.f, 0.f, 0.f, 0.f, 0.f, 0.f};
  if (c > 0) {
    float m = -1e30f;
    for (u32 i = o + lane; i < o + c; i += 64) m = fmaxf(m, scores[i]);
#pragma unroll
    for (int s = 32; s >= 1; s >>= 1) m = fmaxf(m, __shfl_xor(m, s));
    float den = 0.f;
    for (u32 i = o + lane; i < o + c; i += 64) den += expf(scores[i] - m);
#pragma unroll
    for (int s = 32; s >= 1; s >>= 1) den += __shfl_xor(den, s);
    float invden = 1.0f / den;
    for (u32 i = o; i < o + c; ++i) {
      int d = (int)csrS_dst[i];
      float w = expf(scores[i] - m) * invden;
      const u16* vp = vmat + (size_t)d * FIN;
#pragma unroll
      for (int k = 0; k < 6; ++k) acc[k] = fmaf(w, bf2f(vp[lane + 64 * k]), acc[k]);
    }
  }
  const float* xp = x + (size_t)node * FIN;
#pragma unroll
  for (int k = 0; k < 6; ++k)
    xf[(size_t)node * FIN + lane + 64 * k] = f2bf(acc[k] + xp[lane + 64 * k]);
}

// ---------------------------------------------------------------------------
// MFMA bf16 GEMM: C[M,Nc] = A[M,K] @ W[K,Nc], W given transposed bf16 (WT[Nc][K]).
// 128x128 tile, BK=32, 4 waves (2x2 of 64x64), 16x16x32 MFMA, fp32 accum.
// EPI: 0 none, 1 +bias, 2 relu(+bias); OUTBF: write bf16 vs fp32.
// EPI 3: temp[n,r] += sum_cols (acc+bias)*x[n,f]   (atomic, col = r*384+f)
// EPI 4: p_t[n,p]   = sum_r16 (acc+bias)*temp[n,r] (direct, col = p*16+r) + bf16 copy
// ---------------------------------------------------------------------------
template <int EPI, int OUTBF>
__global__ __launch_bounds__(256)
void mgemm_k(const u16* __restrict__ Abf, const u16* __restrict__ WT,
             const float* __restrict__ bias, void* __restrict__ Cp,
             u16* __restrict__ Cbf2, const float* __restrict__ xv,
             float* __restrict__ tmp, int M, int K, int Nc) {
  __shared__ u16 Albuf[2][128 * 32];
  __shared__ u16 Blbuf[2][128 * 32];
  const int t = threadIdx.x;
  const int lane = t & 63;
  const int wave = t >> 6;
  const int wr = wave >> 1, wc = wave & 1;
  const int row0 = blockIdx.y * 128;
  const int col0 = blockIdx.x * 128;
  const int sr = t >> 2;            // 0..63 row within 64-half
  const int sk = (t & 3) * 8;       // k-chunk

  f32x4 acc[4][4] = {};

  auto stage = [&](int buf, int k0) {
#pragma unroll
    for (int h = 0; h < 2; ++h) {
      int ar = row0 + h * 64 + sr;
      if (ar >= M) ar = M - 1;
      GLOAD16(Abf + (size_t)ar * K + k0 + sk, &Albuf[buf][h * 2048 + wave * 512]);
    }
#pragma unroll
    for (int h = 0; h < 2; ++h) {
      int bc = col0 + h * 64 + sr;
      if (bc >= Nc) bc = Nc - 1;
      GLOAD16(WT + (size_t)bc * K + k0 + sk, &Blbuf[buf][h * 2048 + wave * 512]);
    }
  };

  const int nt = K >> 5;
  stage(0, 0);
  int buf = 0;
  for (int tk = 0; tk < nt; ++tk) {
    __syncthreads();                       // drains stage(tk) + WAR safety
    if (tk + 1 < nt) stage(buf ^ 1, (tk + 1) << 5);
    const u16* Al = Albuf[buf];
    const u16* Bl = Blbuf[buf];
    s16x8 a[4], b[4];
#pragma unroll
    for (int m = 0; m < 4; ++m)
      a[m] = *(const s16x8*)(Al + (wr * 64 + m * 16 + (lane & 15)) * 32 + (lane >> 4) * 8);
#pragma unroll
    for (int j = 0; j < 4; ++j)
      b[j] = *(const s16x8*)(Bl + (wc * 64 + j * 16 + (lane & 15)) * 32 + (lane >> 4) * 8);
#pragma unroll
    for (int m = 0; m < 4; ++m)
#pragma unroll
      for (int j = 0; j < 4; ++j)
        acc[m][j] = __builtin_amdgcn_mfma_f32_16x16x32_bf16(a[m], b[j], acc[m][j], 0, 0, 0);
    buf ^= 1;
  }

  // C/D frag: col = lane&15, row = (lane>>4)*4 + reg   [m89/m91]
  if constexpr (EPI <= 2) {
#pragma unroll
    for (int m = 0; m < 4; ++m) {
      int rbase = row0 + wr * 64 + m * 16 + (lane >> 4) * 4;
#pragma unroll
      for (int j = 0; j < 4; ++j) {
        int col = col0 + wc * 64 + j * 16 + (lane & 15);
        if (col >= Nc) continue;
        float bv = (EPI >= 1) ? bias[col] : 0.f;
#pragma unroll
        for (int r = 0; r < 4; ++r) {
          int row = rbase + r;
          if (row >= M) continue;
          float v = acc[m][j][r] + bv;
          if (EPI == 2) v = fmaxf(v, 0.f);
          if (OUTBF) ((u16*)Cp)[(size_t)row * Nc + col] = f2bf(v);
          else       ((float*)Cp)[(size_t)row * Nc + col] = v;
        }
      }
    }
  } else if constexpr (EPI == 3) {
    const int rr = col0 / FIN;     // 384 = 3*128: tile within one r
    const int fb = col0 % FIN;
#pragma unroll
    for (int m = 0; m < 4; ++m) {
#pragma unroll
      for (int r = 0; r < 4; ++r) {
        int row = row0 + wr * 64 + m * 16 + (lane >> 4) * 4 + r;
        float s = 0.f;
        if (row < M) {
#pragma unroll
          for (int j = 0; j < 4; ++j) {
            int cl = wc * 64 + j * 16 + (lane & 15);
            s += (acc[m][j][r] + bias[col0 + cl]) * xv[(size_t)row * FIN + fb + cl];
          }
        }
        s += __shfl_xor(s, 1); s += __shfl_xor(s, 2);
        s += __shfl_xor(s, 4); s += __shfl_xor(s, 8);
        if ((lane & 15) == 0 && row < M) atomicAdd(&tmp[(size_t)row * RD + rr], s);
      }
    }
  } else {  // EPI == 4
#pragma unroll
    for (int m = 0; m < 4; ++m) {
#pragma unroll
      for (int r = 0; r < 4; ++r) {
        int row = row0 + wr * 64 + m * 16 + (lane >> 4) * 4 + r;
        float tv = (row < M) ? tmp[(size_t)row * RD + (lane & 15)] : 0.f;
#pragma unroll
        for (int j = 0; j < 4; ++j) {
          float s = (acc[m][j][r] + bias[col0 + wc * 64 + j * 16 + (lane & 15)]) * tv;
          s += __shfl_xor(s, 1); s += __shfl_xor(s, 2);
          s += __shfl_xor(s, 4); s += __shfl_xor(s, 8);
          if ((lane & 15) == 0 && row < M) {
            int p = (col0 + wc * 64 + j * 16) >> 4;
            ((float*)Cp)[(size_t)row * PD + p] = s;
            Cbf2[(size_t)row * PD + p] = f2bf(s);
          }
        }
      }
    }
  }
}

// ---------------------------------------------------------------------------
// Final: in-place row-normalize p_t, p_g; alignment = dot of normalized rows.
// ---------------------------------------------------------------------------
__global__ void final_k(float* __restrict__ out, int n) {
  int node = (blockIdx.x * blockDim.x + threadIdx.x) >> 6;
  int lane = threadIdx.x & 63;
  if (node >= n) return;
  float* pt = out + n + (size_t)node * PD;
  float* pg = out + n + (size_t)n * PD + (size_t)node * PD;
  float2 t = ((float2*)pt)[lane];
  float2 g = ((float2*)pg)[lane];
  float tt = t.x * t.x + t.y * t.y;
  float gg = g.x * g.x + g.y * g.y;
  float tg = t.x * g.x + t.y * g.y;
#pragma unroll
  for (int s = 32; s >= 1; s >>= 1) {
    tt += __shfl_xor(tt, s);
    gg += __shfl_xor(gg, s);
    tg += __shfl_xor(tg, s);
  }
  float invt = 1.0f / fmaxf(sqrtf(tt), 1e-12f);
  float invg = 1.0f / fmaxf(sqrtf(gg), 1e-12f);
  ((float2*)pt)[lane] = make_float2(t.x * invt, t.y * invt);
  ((float2*)pg)[lane] = make_float2(g.x * invg, g.y * invg);
  if (lane == 0) out[node] = tg * invt * invg;
}

// ---------------------------------------------------------------------------
static void mg(int epi, int outbf, const u16* A, const u16* WT, const float* b,
               void* C, u16* C2, const float* xv, float* tmp,
               int M, int K, int Nc, hipStream_t s) {
  dim3 grid((Nc + 127) / 128, (M + 127) / 128);
#define MGC(E, O) mgemm_k<E, O><<<grid, 256, 0, s>>>(A, WT, b, C, C2, xv, tmp, M, K, Nc)
  if (epi == 0 && outbf) MGC(0, 1);
  else if (epi == 0)     MGC(0, 0);
  else if (epi == 1 && outbf) MGC(1, 1);
  else if (epi == 1)     MGC(1, 0);
  else if (epi == 2)     MGC(2, 1);
  else if (epi == 3)     MGC(3, 0);
  else                   MGC(4, 0);
#undef MGC
}

extern "C" void kernel_launch(void* const* d_in, const int* in_sizes, int n_in,
                              void* d_out, int out_size, void* d_ws, size_t ws_size,
                              hipStream_t stream) {
  const float* x      = (const float*)d_in[0];
  const int*   ei     = (const int*)d_in[1];
  const float* W_gcn1 = (const float*)d_in[2];
  const float* b_gcn1 = (const float*)d_in[3];
  const float* W_ti   = (const float*)d_in[4];
  const float* b_ti   = (const float*)d_in[5];
  const float* W_gi   = (const float*)d_in[6];
  const float* b_gi   = (const float*)d_in[7];
  const float* W_v    = (const float*)d_in[8];
  const float* b_v    = (const float*)d_in[9];
  const float* Wl1    = (const float*)d_in[10];
  const float* bl1    = (const float*)d_in[11];
  const float* Wl2    = (const float*)d_in[12];
  const float* bl2    = (const float*)d_in[13];
  const float* Wr1    = (const float*)d_in[14];
  const float* br1    = (const float*)d_in[15];
  const float* Wr2    = (const float*)d_in[16];
  const float* br2    = (const float*)d_in[17];
  const float* W_gcn2 = (const float*)d_in[18];
  const float* b_gcn2 = (const float*)d_in[19];
  const float* W_gp   = (const float*)d_in[20];
  const float* b_gp   = (const float*)d_in[21];

  const int n = in_sizes[0] / FIN;   // 50000
  const int E = in_sizes[1] / 2;     // 500000
  const int* src = ei;
  const int* dst = ei + E;

  // -------- workspace carve (~225 MB) --------
  char* wsp = (char*)d_ws;
  auto carve = [&](size_t bytes) -> void* {
    void* p = (void*)wsp;
    wsp += (bytes + 255) & ~(size_t)255;
    return p;
  };
  u32* cnt_s    = (u32*)carve((size_t)n * 4);
  u32* cnt_d    = (u32*)carve((size_t)n * 4);
  u32* off_s    = (u32*)carve((size_t)n * 4);
  u32* off_d    = (u32*)carve((size_t)n * 4);
  u32* cur_s    = (u32*)carve((size_t)n * 4);
  u32* cur_d    = (u32*)carve((size_t)n * 4);
  u32* bsum     = (u32*)carve(256);
  u32* csrD_src = (u32*)carve((size_t)E * 4);
  u32* csrS_src = (u32*)carve((size_t)E * 4);
  u32* csrS_dst = (u32*)carve((size_t)E * 4);
  float* dinv   = (float*)carve((size_t)n * 4);
  float* scores = (float*)carve((size_t)E * 4);
  float* temp   = (float*)carve((size_t)n * RD * 4);

  u16* xbf    = (u16*)carve((size_t)n * FIN * 2);   // x bf16, later x_fused bf16
  u16* tibf   = (u16*)carve((size_t)n * FIN * 2);   // t_info, later relu_l
  u16* gibf   = (u16*)carve((size_t)n * FIN * 2);   // g_info, later relu_r
  u16* vbf    = (u16*)carve((size_t)n * FIN * 2);   // v
  u16* bufHbf = (u16*)carve((size_t)n * HD * 2);    // xw (both GCNs)
  u16* gembf  = (u16*)carve((size_t)n * HD * 2);    // g_emb
  u16* ptbf   = (u16*)carve((size_t)n * PD * 2);    // p_t bf16 copy
  u16* g2bf   = (u16*)carve((size_t)n * HD * 2);    // g2 bf16 copy

  u16* WgcnlT = (u16*)carve((size_t)FIN * HD * 2);
  u16* WtiT   = (u16*)carve((size_t)FIN * FIN * 2);
  u16* WgiT   = (u16*)carve((size_t)HD * FIN * 2);
  u16* WvT    = (u16*)carve((size_t)FIN * FIN * 2);
  u16* Wl1T   = (u16*)carve((size_t)FIN * 192 * 2);
  u16* Wl2T   = (u16*)carve((size_t)192 * 2048 * 2);
  u16* Wr1T   = (u16*)carve((size_t)FIN * 192 * 2);
  u16* Wr2T   = (u16*)carve((size_t)192 * 6144 * 2);
  u16* Wgcn2T = (u16*)carve((size_t)PD * HD * 2);
  u16* WgpT   = (u16*)carve((size_t)PD * PD * 2);

  float* out    = (float*)d_out;
  float* pt_raw = out + n;
  float* pg_raw = out + n + (size_t)n * PD;
  float* g2     = out + n + (size_t)2 * n * PD;

  u16* relu_l = tibf;   // [N,192] reuse (dead after scores_k)
  u16* relu_r = gibf;
  u16* xf     = xbf;    // x_fused bf16 reuses xbf (dead after v GEMM)

  // 0) conversions
  cvt_k<<<((n * FIN / 4) + 255) / 256, 256, 0, stream>>>(x, xbf, n * FIN / 4);
  auto cvtT = [&](const float* W, u16* WT, int K, int N) {
    cvtT_k<<<((K * N) + 255) / 256, 256, 0, stream>>>(W, WT, K, N);
  };
  cvtT(W_gcn1, WgcnlT, FIN, HD);
  cvtT(W_ti,   WtiT,   FIN, FIN);
  cvtT(W_gi,   WgiT,   HD,  FIN);
  cvtT(W_v,    WvT,    FIN, FIN);
  cvtT(Wl1,    Wl1T,   FIN, 192);
  cvtT(Wl2,    Wl2T,   192, 2048);
  cvtT(Wr1,    Wr1T,   FIN, 192);
  cvtT(Wr2,    Wr2T,   192, 6144);
  cvtT(W_gcn2, Wgcn2T, PD,  HD);
  cvtT(W_gp,   WgpT,   PD,  PD);

  // 1) CSR build + degrees
  hipMemsetAsync(cnt_s, 0, (size_t)n * 4, stream);
  hipMemsetAsync(cnt_d, 0, (size_t)n * 4, stream);
  hist_k<<<(E + 255) / 256, 256, 0, stream>>>(src, dst, cnt_s, cnt_d, E);
  int nb = (n + 1023) / 1024;
  scanA_k<<<nb, 1024, 0, stream>>>(cnt_s, off_s, bsum, n);
  scanB_k<<<1, 64, 0, stream>>>(bsum, nb);
  scanC_k<<<nb, 1024, 0, stream>>>(off_s, cur_s, bsum, n);
  scanA_k<<<nb, 1024, 0, stream>>>(cnt_d, off_d, bsum, n);
  scanB_k<<<1, 64, 0, stream>>>(bsum, nb);
  scanC_k<<<nb, 1024, 0, stream>>>(off_d, cur_d, bsum, n);
  fill_k<<<(E + 255) / 256, 256, 0, stream>>>(src, dst, cur_s, cur_d, csrD_src, csrS_dst, E);
  srcid_k<<<(n + 255) / 256, 256, 0, stream>>>(off_s, cnt_s, csrS_src, n);
  dinv_k<<<(n + 255) / 256, 256, 0, stream>>>(cnt_d, dinv, n);

  // 2) GCN1
  mg(0, 1, xbf, WgcnlT, nullptr, bufHbf, nullptr, nullptr, nullptr, n, FIN, HD, stream);
  gcn_agg_k<0, 1><<<(n + 3) / 4, 256, 0, stream>>>(bufHbf, dinv, off_d, cnt_d, csrD_src,
                                                   b_gcn1, nullptr, gembf, n);

  // 3) Cross fusion
  mg(1, 1, xbf, WtiT, b_ti, tibf, nullptr, nullptr, nullptr, n, FIN, FIN, stream);
  mg(1, 1, gembf, WgiT, b_gi, gibf, nullptr, nullptr, nullptr, n, HD, FIN, stream);
  mg(1, 1, xbf, WvT, b_v, vbf, nullptr, nullptr, nullptr, n, FIN, FIN, stream);
  scores_k<<<(E * 16 + 255) / 256, 256, 0, stream>>>(csrS_src, csrS_dst, tibf, gibf, scores, E);
  attn_k<<<(n + 3) / 4, 256, 0, stream>>>(off_s, cnt_s, csrS_dst, scores, vbf, x, xf, n);

  // 4) Generators
  mg(2, 1, xf, Wl1T, bl1, relu_l, nullptr, nullptr, nullptr, n, FIN, 192, stream);
  mg(2, 1, xf, Wr1T, br1, relu_r, nullptr, nullptr, nullptr, n, FIN, 192, stream);

  hipMemsetAsync(temp, 0, (size_t)n * RD * 4, stream);
  mg(3, 0, relu_r, Wr2T, br2, nullptr, nullptr, x, temp, n, 192, RD * FIN, stream);
  mg(4, 0, relu_l, Wl2T, bl2, pt_raw, ptbf, nullptr, temp, n, 192, PD * RD, stream);

  // 5) GCN2 + projection
  mg(0, 1, ptbf, Wgcn2T, nullptr, bufHbf, nullptr, nullptr, nullptr, n, PD, HD, stream);
  gcn_agg_k<1, 1><<<(n + 3) / 4, 256, 0, stream>>>(bufHbf, dinv, off_d, cnt_d, csrD_src,
                                                   b_gcn2, g2, g2bf, n);
  mg(1, 0, g2bf, WgpT, b_gp, pg_raw, nullptr, nullptr, nullptr, n, HD, PD, stream);

  // 6) normalize + alignment
  final_k<<<(n + 3) / 4, 256, 0, stream>>>(out, n);
}

// Round 3
// 1108.202 us; speedup vs baseline: 3.5614x; 1.1874x over previous
//
#include <hip/hip_runtime.h>

typedef unsigned int u32;
typedef unsigned short u16;
typedef short s16x8 __attribute__((ext_vector_type(8)));
typedef u16 u16x8 __attribute__((ext_vector_type(8)));
typedef float f32x4 __attribute__((ext_vector_type(4)));

#define FIN 384
#define HD  128
#define PD  128
#define RD  16

#define GLOAD16(g, l)                                                          \
  __builtin_amdgcn_global_load_lds(                                            \
      (const __attribute__((address_space(1))) void*)(g),                      \
      (__attribute__((address_space(3))) void*)(l), 16, 0, 0)

__device__ __forceinline__ u16 f2bf(float f) {
  u32 u = __float_as_uint(f);
  u32 r = (u + 0x7fffu + ((u >> 16) & 1u)) >> 16;   // RNE
  return (u16)r;
}
__device__ __forceinline__ float bf2f(u16 h) {
  return __uint_as_float(((u32)h) << 16);
}

// ---------------------------------------------------------------------------
// One descriptor-driven convert kernel for all weights + x.
// mode 0: dst[c*K+k] = bf16(src[k*N+c])   (transpose, dst [N rows][K cols])
// mode 1: dst[i]     = bf16(src[i])
// mode 2: Q-permute:  dst[q*384+f] = bf16(Wr2[(q>>4)*6144 + (q&15)*384 + f])
// ---------------------------------------------------------------------------
struct CvtEnt { const float* s; u16* d; int K, N, mode, blk0; };
struct CvtDesc { CvtEnt e[12]; int n; };

__global__ void cvt_all_k(CvtDesc dsc) {
  int b = blockIdx.x;
  int ei = 0;
  while (ei + 1 < dsc.n && dsc.e[ei + 1].blk0 <= b) ++ei;
  CvtEnt E = dsc.e[ei];
  int i = (b - E.blk0) * 256 + (int)threadIdx.x;
  int tot = E.K * E.N;
  if (i >= tot) return;
  float v;
  if (E.mode == 0) {
    int c = i / E.K, k = i - c * E.K;
    v = E.s[(size_t)k * E.N + c];
  } else if (E.mode == 1) {
    v = E.s[i];
  } else {
    int q = i / 384, f = i - q * 384;
    v = E.s[(size_t)(q >> 4) * 6144 + (q & 15) * 384 + f];
  }
  E.d[i] = f2bf(v);
}

// ---------------------------------------------------------------------------
// Graph preprocessing (concatenated src|dst arrays, one scan over 2n)
// ---------------------------------------------------------------------------
__global__ void hist_k(const int* __restrict__ src, const int* __restrict__ dst,
                       u32* __restrict__ cnt, int n, int E) {
  int i = blockIdx.x * 256 + threadIdx.x;
  if (i < E) {
    atomicAdd(&cnt[src[i]], 1u);
    atomicAdd(&cnt[n + dst[i]], 1u);
  }
}

__global__ __launch_bounds__(1024)
void scanA_k(const u32* __restrict__ cnt, u32* __restrict__ off,
             u32* __restrict__ bsum, int n2) {
  __shared__ u32 sh[1024];
  int i = blockIdx.x * 1024 + (int)threadIdx.x;
  u32 v = (i < n2) ? cnt[i] : 0u;
  sh[threadIdx.x] = v;
  __syncthreads();
  for (int s = 1; s < 1024; s <<= 1) {
    u32 t = (threadIdx.x >= (u32)s) ? sh[threadIdx.x - s] : 0u;
    __syncthreads();
    sh[threadIdx.x] += t;
    __syncthreads();
  }
  if (i < n2) off[i] = sh[threadIdx.x] - v;       // local exclusive
  if (threadIdx.x == 1023) bsum[blockIdx.x] = sh[1023];
}

__global__ void scanB_k(u32* __restrict__ bsum, int nb) {   // 1 wave, chunks of 64
  int l = threadIdx.x;
  u32 carry = 0u;
  for (int base = 0; base < nb; base += 64) {
    u32 v = (base + l < nb) ? bsum[base + l] : 0u;
    for (int s = 1; s < 64; s <<= 1) {
      u32 t = __shfl_up(v, s);
      if (l >= s) v += t;
    }
    if (base + l < nb) bsum[base + l] = v + carry;
    carry += __shfl(v, 63);
  }
}

__global__ __launch_bounds__(1024)
void scanC_k(u32* __restrict__ off, u32* __restrict__ cur,
             const u32* __restrict__ bsum, int n2) {
  int b = blockIdx.x;
  int i = b * 1024 + (int)threadIdx.x;
  if (i >= n2) return;
  u32 add = (b > 0) ? bsum[b - 1] : 0u;
  u32 o = off[i] + add;
  off[i] = o;
  cur[i] = o;
}

// adj[ps in [0,E)]  = dst (src-CSR payload); adj[pd in [E,2E)] = src (dst-CSR payload)
__global__ void fill_k(const int* __restrict__ src, const int* __restrict__ dst,
                       u32* __restrict__ cur, u32* __restrict__ adj, int n, int E) {
  int i = blockIdx.x * 256 + threadIdx.x;
  if (i >= E) return;
  int s = src[i], d = dst[i];
  u32 ps = atomicAdd(&cur[s], 1u);
  adj[ps] = (u32)d;
  u32 pd = atomicAdd(&cur[n + d], 1u);
  adj[pd] = (u32)s;
}

__global__ void srcid_k(const u32* __restrict__ off, const u32* __restrict__ cnt,
                        u32* __restrict__ csrS_src, int n) {
  int node = blockIdx.x * 256 + threadIdx.x;
  if (node >= n) return;
  u32 o = off[node], c = cnt[node];
  for (u32 i = o; i < o + c; ++i) csrS_src[i] = (u32)node;
}

__global__ void dinv_k(const u32* __restrict__ cd, float* __restrict__ dinv, int n) {
  int i = blockIdx.x * 256 + threadIdx.x;
  if (i < n) dinv[i] = 1.0f / sqrtf((float)(cd[i] + 1u));
}

// ---------------------------------------------------------------------------
// GCN aggregation, bf16 in, fp32/bf16 out
// ---------------------------------------------------------------------------
template <int WF32, int WBF>
__global__ void gcn_agg_k(const u16* __restrict__ xw, const float* __restrict__ dinv,
                          const u32* __restrict__ off, const u32* __restrict__ cnt,
                          const u32* __restrict__ nbr, const float* __restrict__ bias,
                          float* __restrict__ outf, u16* __restrict__ outb, int n) {
  int node = (blockIdx.x * blockDim.x + threadIdx.x) >> 6;
  int lane = threadIdx.x & 63;
  if (node >= n) return;
  float di = dinv[node];
  ushort2 v = ((const ushort2*)(xw + (size_t)node * HD))[lane];
  float ax = di * di * bf2f(v.x), ay = di * di * bf2f(v.y);
  u32 o = off[node], c = cnt[node];
  for (u32 i = o; i < o + c; ++i) {
    int s = (int)nbr[i];
    float w = di * dinv[s];
    ushort2 u = ((const ushort2*)(xw + (size_t)s * HD))[lane];
    ax = fmaf(w, bf2f(u.x), ax);
    ay = fmaf(w, bf2f(u.y), ay);
  }
  float2 b = ((const float2*)bias)[lane];
  ax += b.x; ay += b.y;
  if (WF32) ((float2*)(outf + (size_t)node * HD))[lane] = make_float2(ax, ay);
  if (WBF) {
    ushort2 ob; ob.x = f2bf(ax); ob.y = f2bf(ay);
    ((ushort2*)(outb + (size_t)node * HD))[lane] = ob;
  }
}

// ---------------------------------------------------------------------------
// Edge scores; t_info has row stride TS (lives in tv buffer)
// ---------------------------------------------------------------------------
__global__ void scores_k(const u32* __restrict__ csrS_src, const u32* __restrict__ adj,
                         const u16* __restrict__ ti, int TS, const u16* __restrict__ gi,
                         float* __restrict__ scores, int E) {
  int g = blockIdx.x * 256 + threadIdx.x;
  int e = g >> 4, l = g & 15;
  if (e >= E) return;
  const u16* tp = ti + (size_t)csrS_src[e] * TS;
  const u16* gp = gi + (size_t)adj[e] * FIN;
  float dot = 0.f;
#pragma unroll
  for (int c = 0; c < 3; ++c) {
    u16x8 a = *(const u16x8*)(tp + c * 128 + l * 8);
    u16x8 b = *(const u16x8*)(gp + c * 128 + l * 8);
#pragma unroll
    for (int q = 0; q < 8; ++q) dot = fmaf(bf2f(a[q]), bf2f(b[q]), dot);
  }
#pragma unroll
  for (int m2 = 8; m2 >= 1; m2 >>= 1) dot += __shfl_xor(dot, m2);
  if (l == 0) scores[e] = dot * 0.05103103630798288f;  // 1/sqrt(384)
}

// ---------------------------------------------------------------------------
// Fused scatter-softmax + aggregate + residual; v has row stride VS
// ---------------------------------------------------------------------------
__global__ void attn_k(const u32* __restrict__ off, const u32* __restrict__ cnt,
                       const u32* __restrict__ adj, const float* __restrict__ scores,
                       const u16* __restrict__ vmat, int VS, const float* __restrict__ x,
                       u16* __restrict__ xf, int n) {
  int node = (blockIdx.x * blockDim.x + threadIdx.x) >> 6;
  int lane = threadIdx.x & 63;
  if (node >= n) return;
  u32 o = off[node], c = cnt[node];
  float acc[6] = {0.f, 0.f, 0.f, 0.f, 0.f, 0.f};
  if (c > 0) {
    float m = -1e30f;
    for (u32 i = o + lane; i < o + c; i += 64) m = fmaxf(m, scores[i]);
#pragma unroll
    for (int s = 32; s >= 1; s >>= 1) m = fmaxf(m, __shfl_xor(m, s));
    float den = 0.f;
    for (u32 i = o + lane; i < o + c; i += 64) den += expf(scores[i] - m);
#pragma unroll
    for (int s = 32; s >= 1; s >>= 1) den += __shfl_xor(den, s);
    float invden = 1.0f / den;
    for (u32 i = o; i < o + c; ++i) {
      int d = (int)adj[i];
      float w = expf(scores[i] - m) * invden;
      const u16* vp = vmat + (size_t)d * VS;
#pragma unroll
      for (int k = 0; k < 6; ++k) acc[k] = fmaf(w, bf2f(vp[lane + 64 * k]), acc[k]);
    }
  }
  const float* xp = x + (size_t)node * FIN;
#pragma unroll
  for (int k = 0; k < 6; ++k)
    xf[(size_t)node * FIN + lane + 64 * k] = f2bf(acc[k] + xp[lane + 64 * k]);
}

// ---------------------------------------------------------------------------
// MFMA bf16 GEMM: C[M,Nc] = A[M,K] @ W[K,Nc]; A row stride As; W as WT[Nc][K] bf16.
// 128x128 tile, BK=32 double-buffered via global_load_lds, 4 waves, 16x16x32 MFMA.
// EPI 0/1/2: none / +bias / relu(+bias); split-bias: col<bsplit ? bias : bias_b.
// EPI 4 (left): p_t[row,p] = sum_r (acc+bias[col])*tmp[row,r], col = p*16+r.
//               writes fp32 Cp + bf16 Cbf2.
// EPI 5 (Y):    cols q=h*16+r; tmp[row,r] += sum_h Ar[row,h]*acc  (lane-local over
//               the tile's 4 h's, fp32 atomicAdd across the 24 col-tiles).
// ---------------------------------------------------------------------------
template <int EPI, int OUTBF>
__global__ __launch_bounds__(256)
void mgemm_k(const u16* __restrict__ Abf, int As, const u16* __restrict__ WT,
             const float* __restrict__ bias, const float* __restrict__ bias_b, int bsplit,
             void* __restrict__ Cp, u16* __restrict__ Cbf2,
             const u16* __restrict__ Ar, int ArS,
             float* __restrict__ tmp, int M, int K, int Nc) {
  __shared__ u16 Albuf[2][128 * 32];
  __shared__ u16 Blbuf[2][128 * 32];
  const int t = threadIdx.x;
  const int lane = t & 63;
  const int wave = t >> 6;
  const int wr = wave >> 1, wc = wave & 1;
  const int row0 = blockIdx.y * 128;
  const int col0 = blockIdx.x * 128;
  const int sr = t >> 2;            // 0..63 row within 64-half
  const int sk = (t & 3) * 8;       // k-chunk

  f32x4 acc[4][4] = {};

  auto stage = [&](int buf, int k0) {
#pragma unroll
    for (int h = 0; h < 2; ++h) {
      int ar = row0 + h * 64 + sr;
      if (ar >= M) ar = M - 1;
      GLOAD16(Abf + (size_t)ar * As + k0 + sk, &Albuf[buf][h * 2048 + wave * 512]);
    }
#pragma unroll
    for (int h = 0; h < 2; ++h) {
      int bc = col0 + h * 64 + sr;
      if (bc >= Nc) bc = Nc - 1;
      GLOAD16(WT + (size_t)bc * K + k0 + sk, &Blbuf[buf][h * 2048 + wave * 512]);
    }
  };

  const int nt = K >> 5;
  stage(0, 0);
  int buf = 0;
  for (int tk = 0; tk < nt; ++tk) {
    __syncthreads();                       // drains stage(tk) + WAR safety
    if (tk + 1 < nt) stage(buf ^ 1, (tk + 1) << 5);
    const u16* Al = Albuf[buf];
    const u16* Bl = Blbuf[buf];
    s16x8 a[4], b[4];
#pragma unroll
    for (int m = 0; m < 4; ++m)
      a[m] = *(const s16x8*)(Al + (wr * 64 + m * 16 + (lane & 15)) * 32 + (lane >> 4) * 8);
#pragma unroll
    for (int j = 0; j < 4; ++j)
      b[j] = *(const s16x8*)(Bl + (wc * 64 + j * 16 + (lane & 15)) * 32 + (lane >> 4) * 8);
#pragma unroll
    for (int m = 0; m < 4; ++m)
#pragma unroll
      for (int j = 0; j < 4; ++j)
        acc[m][j] = __builtin_amdgcn_mfma_f32_16x16x32_bf16(a[m], b[j], acc[m][j], 0, 0, 0);
    buf ^= 1;
  }

  // C/D frag: col = lane&15, row = (lane>>4)*4 + reg   [m89/m91]
  if constexpr (EPI <= 2) {
#pragma unroll
    for (int m = 0; m < 4; ++m) {
      int rbase = row0 + wr * 64 + m * 16 + (lane >> 4) * 4;
#pragma unroll
      for (int j = 0; j < 4; ++j) {
        int col = col0 + wc * 64 + j * 16 + (lane & 15);
        if (col >= Nc) continue;
        float bv = 0.f;
        if (EPI >= 1) bv = (col < bsplit) ? bias[col] : bias_b[col - bsplit];
#pragma unroll
        for (int r = 0; r < 4; ++r) {
          int row = rbase + r;
          if (row >= M) continue;
          float v = acc[m][j][r] + bv;
          if (EPI == 2) v = fmaxf(v, 0.f);
          if (OUTBF) ((u16*)Cp)[(size_t)row * Nc + col] = f2bf(v);
          else       ((float*)Cp)[(size_t)row * Nc + col] = v;
        }
      }
    }
  } else if constexpr (EPI == 4) {
#pragma unroll
    for (int m = 0; m < 4; ++m) {
#pragma unroll
      for (int r = 0; r < 4; ++r) {
        int row = row0 + wr * 64 + m * 16 + (lane >> 4) * 4 + r;
        float tv = (row < M) ? tmp[(size_t)row * RD + (lane & 15)] : 0.f;
#pragma unroll
        for (int j = 0; j < 4; ++j) {
          float s = (acc[m][j][r] + bias[col0 + wc * 64 + j * 16 + (lane & 15)]) * tv;
          s += __shfl_xor(s, 1); s += __shfl_xor(s, 2);
          s += __shfl_xor(s, 4); s += __shfl_xor(s, 8);
          if ((lane & 15) == 0 && row < M) {
            int p = (col0 + wc * 64 + j * 16) >> 4;
            ((float*)Cp)[(size_t)row * PD + p] = s;
            Cbf2[(size_t)row * PD + p] = f2bf(s);
          }
        }
      }
    }
  } else {  // EPI == 5
    const int h0 = (col0 >> 4) + wc * 4;   // 4 consecutive h's for j=0..3
#pragma unroll
    for (int m = 0; m < 4; ++m) {
#pragma unroll
      for (int r = 0; r < 4; ++r) {
        int row = row0 + wr * 64 + m * 16 + (lane >> 4) * 4 + r;
        if (row >= M) continue;
        ushort4 arv = *(const ushort4*)(Ar + (size_t)row * ArS + h0);
        float s = bf2f(arv.x) * acc[m][0][r] + bf2f(arv.y) * acc[m][1][r] +
                  bf2f(arv.z) * acc[m][2][r] + bf2f(arv.w) * acc[m][3][r];
        atomicAdd(&tmp[(size_t)row * RD + (lane & 15)], s);
      }
    }
  }
}

// ---------------------------------------------------------------------------
// Final: in-place row-normalize p_t, p_g; alignment = dot of normalized rows.
// ---------------------------------------------------------------------------
__global__ void final_k(float* __restrict__ out, int n) {
  int node = (blockIdx.x * blockDim.x + threadIdx.x) >> 6;
  int lane = threadIdx.x & 63;
  if (node >= n) return;
  float* pt = out + n + (size_t)node * PD;
  float* pg = out + n + (size_t)n * PD + (size_t)node * PD;
  float2 t = ((float2*)pt)[lane];
  float2 g = ((float2*)pg)[lane];
  float tt = t.x * t.x + t.y * t.y;
  float gg = g.x * g.x + g.y * g.y;
  float tg = t.x * g.x + t.y * g.y;
#pragma unroll
  for (int s = 32; s >= 1; s >>= 1) {
    tt += __shfl_xor(tt, s);
    gg += __shfl_xor(gg, s);
    tg += __shfl_xor(tg, s);
  }
  float invt = 1.0f / fmaxf(sqrtf(tt), 1e-12f);
  float invg = 1.0f / fmaxf(sqrtf(gg), 1e-12f);
  ((float2*)pt)[lane] = make_float2(t.x * invt, t.y * invt);
  ((float2*)pg)[lane] = make_float2(g.x * invg, g.y * invg);
  if (lane == 0) out[node] = tg * invt * invg;
}

// ---------------------------------------------------------------------------
struct MgArgs {
  const u16* A; int As; const u16* WT;
  const float* b; const float* b2; int bsplit;
  void* C; u16* C2; const u16* Ar; int ArS; float* tmp;
  int M, K, Nc;
};
template <int EPI, int OUTBF>
static void mg(const MgArgs& a, hipStream_t s) {
  dim3 grid((a.Nc + 127) / 128, (a.M + 127) / 128);
  mgemm_k<EPI, OUTBF><<<grid, 256, 0, s>>>(a.A, a.As, a.WT, a.b, a.b2, a.bsplit,
                                           a.C, a.C2, a.Ar, a.ArS, a.tmp,
                                           a.M, a.K, a.Nc);
}

extern "C" void kernel_launch(void* const* d_in, const int* in_sizes, int n_in,
                              void* d_out, int out_size, void* d_ws, size_t ws_size,
                              hipStream_t stream) {
  const float* x      = (const float*)d_in[0];
  const int*   ei     = (const int*)d_in[1];
  const float* W_gcn1 = (const float*)d_in[2];
  const float* b_gcn1 = (const float*)d_in[3];
  const float* W_ti   = (const float*)d_in[4];
  const float* b_ti   = (const float*)d_in[5];
  const float* W_gi   = (const float*)d_in[6];
  const float* b_gi   = (const float*)d_in[7];
  const float* W_v    = (const float*)d_in[8];
  const float* b_v    = (const float*)d_in[9];
  const float* Wl1    = (const float*)d_in[10];
  const float* bl1    = (const float*)d_in[11];
  const float* Wl2    = (const float*)d_in[12];
  const float* bl2    = (const float*)d_in[13];
  const float* Wr1    = (const float*)d_in[14];
  const float* br1    = (const float*)d_in[15];
  const float* Wr2    = (const float*)d_in[16];
  const float* br2    = (const float*)d_in[17];
  const float* W_gcn2 = (const float*)d_in[18];
  const float* b_gcn2 = (const float*)d_in[19];
  const float* W_gp   = (const float*)d_in[20];
  const float* b_gp   = (const float*)d_in[21];

  const int n = in_sizes[0] / FIN;   // 50000
  const int E = in_sizes[1] / 2;     // 500000
  const int* src = ei;
  const int* dst = ei + E;

  // -------- workspace carve (~261 MB) --------
  char* wsp = (char*)d_ws;
  auto carve = [&](size_t bytes) -> void* {
    void* p = (void*)wsp;
    wsp += (bytes + 255) & ~(size_t)255;
    return p;
  };
  u32* cnt      = (u32*)carve((size_t)2 * n * 4);   // [src | dst]
  u32* off      = (u32*)carve((size_t)2 * n * 4);
  u32* cur      = (u32*)carve((size_t)2 * n * 4);
  u32* bsum     = (u32*)carve(512);
  u32* adj      = (u32*)carve((size_t)2 * E * 4);   // [src-CSR dsts | dst-CSR srcs]
  u32* csrS_src = (u32*)carve((size_t)E * 4);
  float* dinv   = (float*)carve((size_t)n * 4);
  float* scores = (float*)carve((size_t)E * 4);
  float* temp   = (float*)carve((size_t)n * RD * 4);

  u16* xbf    = (u16*)carve((size_t)n * FIN * 2);       // x bf16 (pristine)
  u16* tvbf   = (u16*)carve((size_t)n * 2 * FIN * 2);   // [t_info | v]; later lrbf
  u16* gibf   = (u16*)carve((size_t)n * FIN * 2);       // g_info
  u16* xfbf   = (u16*)carve((size_t)n * FIN * 2);       // x_fused
  u16* bufHbf = (u16*)carve((size_t)n * HD * 2);        // xw (both GCNs)
  u16* gembf  = (u16*)carve((size_t)n * HD * 2);
  u16* ptbf   = (u16*)carve((size_t)n * PD * 2);
  u16* g2bf   = (u16*)carve((size_t)n * HD * 2);

  u16* WgcnT  = (u16*)carve((size_t)HD * FIN * 2);      // [128][384]
  u16* WtvT   = (u16*)carve((size_t)2 * FIN * FIN * 2); // [768][384]
  u16* WgiT   = (u16*)carve((size_t)FIN * HD * 2);      // [384][128]
  u16* WlrT   = (u16*)carve((size_t)FIN * FIN * 2);     // [384][384]
  u16* Wl2T   = (u16*)carve((size_t)2048 * 192 * 2);
  u16* QT     = (u16*)carve((size_t)3072 * FIN * 2);    // permuted Wr2
  u16* BrT    = (u16*)carve((size_t)RD * FIN * 2);      // br2 reshaped [16][384]
  u16* Wgcn2T = (u16*)carve((size_t)HD * PD * 2);
  u16* WgpT   = (u16*)carve((size_t)PD * PD * 2);

  u16* lrbf = tvbf;   // [relu_l | relu_r], stride 384; tv dead after attn_k

  float* out    = (float*)d_out;
  float* pt_raw = out + n;
  float* pg_raw = out + n + (size_t)n * PD;
  float* g2     = out + n + (size_t)2 * n * PD;

  // 0) all converts in one launch
  CvtDesc dsc;
  int nent = 0, blk = 0;
  auto addent = [&](const float* s, u16* d, int K, int N, int mode) {
    dsc.e[nent] = {s, d, K, N, mode, blk};
    blk += (K * N + 255) / 256;
    ++nent;
  };
  addent(x,      xbf,    n * FIN, 1, 1);
  addent(W_gcn1, WgcnT,  FIN, HD,  0);
  addent(W_ti,   WtvT,   FIN, FIN, 0);
  addent(W_v,    WtvT + (size_t)FIN * FIN, FIN, FIN, 0);
  addent(W_gi,   WgiT,   HD,  FIN, 0);
  addent(Wl1,    WlrT,   FIN, 192, 0);
  addent(Wr1,    WlrT + (size_t)192 * FIN, FIN, 192, 0);
  addent(Wl2,    Wl2T,   192, 2048, 0);
  addent(Wr2,    QT,     FIN, 3072, 2);
  addent(br2,    BrT,    RD * FIN, 1, 1);
  addent(W_gcn2, Wgcn2T, PD, HD, 0);
  addent(W_gp,   WgpT,   PD, PD, 0);
  dsc.n = nent;
  cvt_all_k<<<blk, 256, 0, stream>>>(dsc);

  // 1) CSR build + degrees (one concatenated scan over 2n)
  hipMemsetAsync(cnt, 0, (size_t)2 * n * 4, stream);
  hist_k<<<(E + 255) / 256, 256, 0, stream>>>(src, dst, cnt, n, E);
  int n2 = 2 * n;
  int nb = (n2 + 1023) / 1024;
  scanA_k<<<nb, 1024, 0, stream>>>(cnt, off, bsum, n2);
  scanB_k<<<1, 64, 0, stream>>>(bsum, nb);
  scanC_k<<<nb, 1024, 0, stream>>>(off, cur, bsum, n2);
  fill_k<<<(E + 255) / 256, 256, 0, stream>>>(src, dst, cur, adj, n, E);
  srcid_k<<<(n + 255) / 256, 256, 0, stream>>>(off, cnt, csrS_src, n);
  dinv_k<<<(n + 255) / 256, 256, 0, stream>>>(cnt + n, dinv, n);

  MgArgs a{};
  a.M = n;

  // 2) GCN1: xw = x @ W_gcn1 -> aggregate
  a = {xbf, FIN, WgcnT, nullptr, nullptr, 1 << 30, bufHbf, nullptr, nullptr, 0, nullptr, n, FIN, HD};
  mg<0, 1>(a, stream);
  gcn_agg_k<0, 1><<<(n + 3) / 4, 256, 0, stream>>>(bufHbf, dinv, off + n, cnt + n, adj,
                                                   b_gcn1, nullptr, gembf, n);

  // 3) Cross fusion: [t_info | v] in one GEMM; g_info; scores; attn
  a = {xbf, FIN, WtvT, b_ti, b_v, FIN, tvbf, nullptr, nullptr, 0, nullptr, n, FIN, 2 * FIN};
  mg<1, 1>(a, stream);
  a = {gembf, HD, WgiT, b_gi, nullptr, 1 << 30, gibf, nullptr, nullptr, 0, nullptr, n, HD, FIN};
  mg<1, 1>(a, stream);
  scores_k<<<(E * 16 + 255) / 256, 256, 0, stream>>>(csrS_src, adj, tvbf, 2 * FIN, gibf, scores, E);
  attn_k<<<(n + 3) / 4, 256, 0, stream>>>(off, cnt, adj, scores, tvbf + FIN, 2 * FIN, x, xfbf, n);

  // 4) Generators: [relu_l | relu_r] in one GEMM (overwrites tv buffer)
  a = {xfbf, FIN, WlrT, bl1, br1, 192, lrbf, nullptr, nullptr, 0, nullptr, n, FIN, FIN};
  mg<2, 1>(a, stream);

  // right path: temp = x@Br (c-GEMM, direct write) + Y-GEMM fused reduce (atomic)
  a = {xbf, FIN, BrT, nullptr, nullptr, 1 << 30, temp, nullptr, nullptr, 0, nullptr, n, FIN, RD};
  mg<0, 0>(a, stream);
  a = {xbf, FIN, QT, nullptr, nullptr, 1 << 30, nullptr, nullptr, lrbf + 192, FIN, temp, n, FIN, 3072};
  mg<5, 0>(a, stream);

  // left path fused: p_t[n,p] = sum_r (relu_l@Wl2 + bl2)[n,p*16+r] * temp[n,r]
  a = {lrbf, FIN, Wl2T, bl2, nullptr, 1 << 30, pt_raw, ptbf, nullptr, 0, temp, n, 192, PD * RD};
  mg<4, 0>(a, stream);

  // 5) GCN2 + projection
  a = {ptbf, PD, Wgcn2T, nullptr, nullptr, 1 << 30, bufHbf, nullptr, nullptr, 0, nullptr, n, PD, HD};
  mg<0, 1>(a, stream);
  gcn_agg_k<1, 1><<<(n + 3) / 4, 256, 0, stream>>>(bufHbf, dinv, off + n, cnt + n, adj,
                                                   b_gcn2, g2, g2bf, n);
  a = {g2bf, HD, WgpT, b_gp, nullptr, 1 << 30, pg_raw, nullptr, nullptr, 0, nullptr, n, HD, PD};
  mg<1, 0>(a, stream);

  // 6) normalize + alignment
  final_k<<<(n + 3) / 4, 256, 0, stream>>>(out, n);
}